// Round 8
// baseline (346.161 us; speedup 1.0000x reference)
//
#include <hip/hip_runtime.h>
#include <math.h>

#define S_LEN 2048
#define DM 1024
#define NH 16
#define HD 64
#define DFF 4096
#define MROWS 4096  // S_LEN * 2 batch

typedef unsigned short u16;
typedef __attribute__((ext_vector_type(8))) __bf16 bf16x8;
typedef __attribute__((ext_vector_type(4))) float f32x4;
typedef __attribute__((ext_vector_type(16))) float f32x16;
typedef __attribute__((ext_vector_type(4))) int int32x4;

__device__ __forceinline__ u16 f2bf(float f) {
  unsigned u = __float_as_uint(f);
  unsigned r = (u + 0x7fffu + ((u >> 16) & 1u)) >> 16;  // RNE
  return (u16)r;
}

__device__ __forceinline__ float bf2f(u16 u) {
  return __uint_as_float((unsigned)u << 16);
}

__device__ __forceinline__ unsigned cvtpk_bf16(float lo, float hi) {
  unsigned r;
  asm("v_cvt_pk_bf16_f32 %0, %1, %2" : "=v"(r) : "v"(lo), "v"(hi));
  return r;
}

__device__ __forceinline__ void gload_lds16(const void* g, void* l) {
  __builtin_amdgcn_global_load_lds((__attribute__((address_space(1))) void*)g,
                                   (__attribute__((address_space(3))) void*)l, 16, 0, 0);
}

// ---------- 4x fused transpose + fp32->bf16 weights (1024x1024): W -> Wt ----------
__global__ __launch_bounds__(256) void k_transpose4(const float* __restrict__ W0, const float* __restrict__ W1,
                                                    const float* __restrict__ W2, const float* __restrict__ W3,
                                                    u16* __restrict__ T0, u16* __restrict__ T1,
                                                    u16* __restrict__ T2, u16* __restrict__ T3) {
  __shared__ float tile[32][33];
  const float* W = blockIdx.z == 0 ? W0 : blockIdx.z == 1 ? W1 : blockIdx.z == 2 ? W2 : W3;
  u16* Wt = blockIdx.z == 0 ? T0 : blockIdx.z == 1 ? T1 : blockIdx.z == 2 ? T2 : T3;
  int n0 = blockIdx.x * 32, k0 = blockIdx.y * 32;
  int tx = threadIdx.x & 31, ty = threadIdx.x >> 5;
  #pragma unroll
  for (int r = ty; r < 32; r += 8) tile[r][tx] = W[(size_t)(k0 + r) * 1024 + n0 + tx];
  __syncthreads();
  #pragma unroll
  for (int r = ty; r < 32; r += 8) Wt[(size_t)(n0 + r) * 1024 + k0 + tx] = f2bf(tile[tx][r]);
}

__global__ __launch_bounds__(256) void k_transpose_bf16(const float* __restrict__ W,
                                                        u16* __restrict__ Wt, int K, int N) {
  __shared__ float tile[32][33];
  int n0 = blockIdx.x * 32, k0 = blockIdx.y * 32;
  int tx = threadIdx.x & 31, ty = threadIdx.x >> 5;
  #pragma unroll
  for (int r = ty; r < 32; r += 8) tile[r][tx] = W[(size_t)(k0 + r) * N + n0 + tx];
  __syncthreads();
  #pragma unroll
  for (int r = ty; r < 32; r += 8) Wt[(size_t)(n0 + r) * K + k0 + tx] = f2bf(tile[tx][r]);
}

__global__ __launch_bounds__(256) void k_f2bf4(const float4* __restrict__ in,
                                               ushort4* __restrict__ out, int n4) {
  int i = blockIdx.x * 256 + threadIdx.x;
  if (i >= n4) return;
  float4 v = in[i];
  ushort4 o;
  o.x = f2bf(v.x); o.y = f2bf(v.y); o.z = f2bf(v.z); o.w = f2bf(v.w);
  out[i] = o;
}

__global__ __launch_bounds__(256) void k_rope_table(float* __restrict__ cosT,
                                                    float* __restrict__ sinT) {
  int idx = blockIdx.x * 256 + threadIdx.x;
  if (idx >= S_LEN * 32) return;
  int s = idx >> 5, i = idx & 31;
  float inv = powf(10000.f, -(float)(2 * i) / 64.f);
  float ang = (float)s * inv;
  cosT[idx] = cosf(ang);
  sinT[idx] = sinf(ang);
}

__global__ __launch_bounds__(256) void k_cat3(const float* __restrict__ a, const float* __restrict__ b,
                                              const float* __restrict__ c, float* __restrict__ o) {
  int i = blockIdx.x * 256 + threadIdx.x;
  if (i >= 3072) return;
  o[i] = i < 1024 ? a[i] : (i < 2048 ? b[i - 1024] : c[i - 2048]);
}

// ---------- mask tile flags: 0 = all pass (>=0.1), 1 = mixed/masked ----------
__global__ __launch_bounds__(256) void k_mask_flags(const float* __restrict__ mask,
                                                    unsigned char* __restrict__ flags) {
  int kt = blockIdx.x, qt = blockIdx.y;
  const float* mp = mask + (size_t)(qt * 64) * S_LEN + kt * 64;
  int tr = threadIdx.x >> 2;
  int tc = (threadIdx.x & 3) * 16;
  int ok = 1;
  #pragma unroll
  for (int c = 0; c < 16; c += 4) {
    float4 v = *(const float4*)(mp + (size_t)tr * S_LEN + tc + c);
    ok &= (v.x >= 0.1f) & (v.y >= 0.1f) & (v.z >= 0.1f) & (v.w >= 0.1f);
  }
  ok = __all(ok) ? 1 : 0;
  __shared__ int sh[4];
  if ((threadIdx.x & 63) == 0) sh[threadIdx.x >> 6] = ok;
  __syncthreads();
  if (threadIdx.x == 0) flags[qt * 32 + kt] = (sh[0] & sh[1] & sh[2] & sh[3]) ? 0 : 1;
}

// ---------- 256x256-tile pipelined bf16 GEMM ----------
enum { EPI_F32 = 0, EPI_RELU_BF16 = 2, EPI_PARTB = 4, EPI_BF16 = 5 };

template <int EPI>
__global__ __launch_bounds__(512, 2) void k_gemm256(const u16* __restrict__ A,
                                                    const u16* __restrict__ Bt,
                                                    const float* __restrict__ bias,
                                                    float* __restrict__ Cf, u16* __restrict__ Cb,
                                                    int M, int N, int K, int ldc, int Kc) {
  __shared__ __attribute__((aligned(16))) u16 As[4][256 * 32];
  __shared__ __attribute__((aligned(16))) u16 Bs[4][256 * 32];

  int nx = gridDim.x;
  int nwg = nx * gridDim.y;
  int flat = blockIdx.y * nx + blockIdx.x;
  int id = (flat & 7) * (nwg >> 3) + (flat >> 3);
  int n0 = (id % nx) * 256;
  int m0 = (id / nx) * 256;
  int kz = blockIdx.z * Kc;

  int tid = threadIdx.x;
  int lane = tid & 63, w = tid >> 6;
  int wm = (w >> 2) * 128, wn = (w & 3) * 64;
  int l15 = lane & 15, l4 = lane >> 4;
  int NT = Kc >> 5;

  const u16* aS[2];
  const u16* bS[2];
  int dslot[2];
  #pragma unroll
  for (int j = 0; j < 2; ++j) {
    int P = j * 512 + tid;
    int r = P >> 2;
    int sl = (P & 3) ^ (r & 3);
    aS[j] = A + (size_t)(m0 + r) * K + kz + sl * 8;
    bS[j] = Bt + (size_t)(n0 + r) * K + kz + sl * 8;
    dslot[j] = j * 512 + w * 64;
  }

  f32x4 acc[8][4] = {};

  #pragma unroll
  for (int t = 0; t < 3; ++t) {
    #pragma unroll
    for (int j = 0; j < 2; ++j) {
      gload_lds16(aS[j] + t * 32, &As[t][dslot[j] * 8]);
      gload_lds16(bS[j] + t * 32, &Bs[t][dslot[j] * 8]);
    }
  }

  for (int t = 0; t < NT; ++t) {
    int buf = t & 3;
    if (t < NT - 2) asm volatile("s_waitcnt vmcnt(8)" ::: "memory");
    else if (t == NT - 2) asm volatile("s_waitcnt vmcnt(4)" ::: "memory");
    else asm volatile("s_waitcnt vmcnt(0)" ::: "memory");
    __builtin_amdgcn_s_barrier();

    if (t + 3 < NT) {
      int tn = t + 3;
      int bn = tn & 3;
      #pragma unroll
      for (int j = 0; j < 2; ++j) {
        gload_lds16(aS[j] + tn * 32, &As[bn][dslot[j] * 8]);
        gload_lds16(bS[j] + tn * 32, &Bs[bn][dslot[j] * 8]);
      }
    }

    bf16x8 af[8], bq[4];
    #pragma unroll
    for (int m = 0; m < 8; ++m) {
      int r = wm + m * 16 + l15;
      af[m] = *(const bf16x8*)&As[buf][r * 32 + (l4 ^ (r & 3)) * 8];
    }
    #pragma unroll
    for (int n = 0; n < 4; ++n) {
      int r = wn + n * 16 + l15;
      bq[n] = *(const bf16x8*)&Bs[buf][r * 32 + (l4 ^ (r & 3)) * 8];
    }
    __builtin_amdgcn_s_setprio(1);
    #pragma unroll
    for (int m = 0; m < 8; ++m)
      #pragma unroll
      for (int n = 0; n < 4; ++n)
        acc[m][n] = __builtin_amdgcn_mfma_f32_16x16x32_bf16(af[m], bq[n], acc[m][n], 0, 0, 0);
    __builtin_amdgcn_s_setprio(0);
  }

  size_t zoff = (size_t)blockIdx.z * M * ldc;
  #pragma unroll
  for (int m = 0; m < 8; ++m) {
    #pragma unroll
    for (int n = 0; n < 4; ++n) {
      int col = n0 + wn + n * 16 + l15;
      float bv = (EPI == EPI_PARTB) ? 0.f : bias[col];
      #pragma unroll
      for (int r = 0; r < 4; ++r) {
        int row = m0 + wm + m * 16 + l4 * 4 + r;
        float v = acc[m][n][r] + bv;
        size_t o = (size_t)row * ldc + col;
        if (EPI == EPI_F32) Cf[o] = v;
        else if (EPI == EPI_RELU_BF16) Cb[o] = f2bf(fmaxf(v, 0.f));
        else if (EPI == EPI_BF16) Cb[o] = f2bf(v);
        else Cb[zoff + o] = f2bf(v);
      }
    }
  }
}

// ---------- RoPE + head-split (bf16 QKV in); Q pre-scaled by log2(e)/sqrt(HD) ----------
#define QSCALE 0.180336881f
__global__ __launch_bounds__(256) void k_rope_heads(const u16* __restrict__ QKVb,
                                                    const float* __restrict__ cosT,
                                                    const float* __restrict__ sinT,
                                                    u16* __restrict__ Qh, u16* __restrict__ Kh,
                                                    u16* __restrict__ Vt) {
  int idx = blockIdx.x * 256 + threadIdx.x;
  if (idx >= MROWS * 512) return;
  int m = idx >> 9, c2 = idx & 511;
  int h = c2 >> 5, i = c2 & 31, d = 2 * i;
  int s = m >> 1, b = m & 1;
  int bh = b * NH + h;
  size_t base = (size_t)m * 3072 + h * 64 + d;
  float q0 = bf2f(QKVb[base]), q1 = bf2f(QKVb[base + 1]);
  float k0 = bf2f(QKVb[base + 1024]), k1 = bf2f(QKVb[base + 1025]);
  float v0 = bf2f(QKVb[base + 2048]), v1 = bf2f(QKVb[base + 2049]);
  float c = cosT[s * 32 + i], sn = sinT[s * 32 + i];
  size_t ho = ((size_t)bh * S_LEN + s) * 64 + d;
  Qh[ho]     = f2bf((q0 * c - q1 * sn) * QSCALE);
  Qh[ho + 1] = f2bf((q1 * c + q0 * sn) * QSCALE);
  Kh[ho]     = f2bf(k0 * c - k1 * sn);
  Kh[ho + 1] = f2bf(k1 * c + k0 * sn);
  size_t vo = ((size_t)bh * 64 + d) * S_LEN + s;
  Vt[vo] = f2bf(v0);
  Vt[vo + S_LEN] = f2bf(v1);
}

// ---------- flash attention, KV-split-2: each block does 1024 keys for 128 q ----------
// 4 waves x 32 q; KVB=64 double-buffered (32 KB LDS -> 4 blocks/CU, 4 waves/SIMD).
// Unnormalized O + (m,l) out; k_attn_merge combines the two halves.
__global__ __launch_bounds__(256, 4) void k_attn(const u16* __restrict__ Qh, const u16* __restrict__ Kh,
                                                 const u16* __restrict__ Vt,
                                                 const float* __restrict__ mask,
                                                 const unsigned char* __restrict__ flags,
                                                 u16* __restrict__ Oh, float2* __restrict__ ml) {
  __shared__ __attribute__((aligned(16))) u16 Ks[2][64 * 64];
  __shared__ __attribute__((aligned(16))) u16 Vs[2][64 * 64];
  // 1024 blocks: xcd = f&7 owns 4 heads; per head 32 blocks (2 halves x 16 q-blocks)
  int f = blockIdx.y * gridDim.x + blockIdx.x;  // grid (32, 32)
  int xcd = f & 7, ii = f >> 3;
  int bh = xcd * 4 + (ii >> 5);
  int r5 = ii & 31;
  int hf = r5 >> 4;        // KV half: keys [hf*1024, hf*1024+1024)
  int q0 = (r5 & 15) * 128;
  int tid = threadIdx.x, lane = tid & 63, w = tid >> 6;
  int l31 = lane & 31, l5 = lane >> 5;

  int qrow = q0 + w * 32 + l31;
  int qt = qrow >> 6;  // wave-uniform

  bf16x8 qf[4];
  {
    const u16* qp = Qh + ((size_t)bh * S_LEN + qrow) * 64 + l5 * 8;
    #pragma unroll
    for (int dc = 0; dc < 4; ++dc) qf[dc] = *(const bf16x8*)(qp + dc * 16);
  }

  // uniform staging bases for this half (advance per tile); per-lane invariant offsets
  const u16* KbaseH = Kh + ((size_t)bh * S_LEN + hf * 1024) * 64;
  const u16* VbaseH = Vt + (size_t)bh * 64 * S_LEN + hf * 1024;
  int koff[2], voff[2];
  #pragma unroll
  for (int i = 0; i < 2; ++i) {
    int s = i * 256 + tid;           // 16B slot in [0,512)
    int kr = s >> 3, kslot = s & 7;
    koff[i] = kr * 64 + (kslot ^ (kr & 7)) * 8;
    int vr = s >> 3, vslot = s & 7;
    voff[i] = vr * S_LEN + (vslot ^ (vr & 7)) * 8;
  }

  float m_run = -1e30f, l_run = 0.f;
  f32x16 oA = {}, oB = {};

  // prologue: stage tile 0 -> buf 0
  #pragma unroll
  for (int i = 0; i < 2; ++i) {
    gload_lds16(KbaseH + koff[i], &Ks[0][(i * 256 + tid) * 8]);
    gload_lds16(VbaseH + voff[i], &Vs[0][(i * 256 + tid) * 8]);
  }

#define ATTN_TILE(T, CUR)                                                                     \
  do {                                                                                        \
    asm volatile("s_waitcnt vmcnt(0)" ::: "memory");                                          \
    __builtin_amdgcn_s_barrier();                                                             \
    if ((T) + 1 < 16) {                                                                       \
      const u16* kt_ = KbaseH + (size_t)((T) + 1) * 4096;                                     \
      const u16* vt_ = VbaseH + ((T) + 1) * 64;                                               \
      _Pragma("unroll")                                                                       \
      for (int i = 0; i < 2; ++i) {                                                           \
        gload_lds16(kt_ + koff[i], &Ks[(CUR) ^ 1][(i * 256 + tid) * 8]);                      \
        gload_lds16(vt_ + voff[i], &Vs[(CUR) ^ 1][(i * 256 + tid) * 8]);                      \
      }                                                                                       \
    }                                                                                         \
    f32x16 sA = {}, sB = {};                                                                  \
    _Pragma("unroll")                                                                         \
    for (int dc = 0; dc < 4; ++dc) {                                                          \
      int r0 = l31, r1 = 32 + l31;                                                            \
      bf16x8 ka0 = *(const bf16x8*)&Ks[CUR][r0 * 64 + (((dc * 2 + l5)) ^ (r0 & 7)) * 8];      \
      bf16x8 ka1 = *(const bf16x8*)&Ks[CUR][r1 * 64 + (((dc * 2 + l5)) ^ (r1 & 7)) * 8];      \
      sA = __builtin_amdgcn_mfma_f32_32x32x16_bf16(ka0, qf[dc], sA, 0, 0, 0);                 \
      sB = __builtin_amdgcn_mfma_f32_32x32x16_bf16(ka1, qf[dc], sB, 0, 0, 0);                 \
    }                                                                                         \
    int kv0abs = hf * 1024 + (T) * 64;                                                        \
    int fl = flags[qt * 32 + (kv0abs >> 6)];                                                  \
    if (fl) {                                                                                 \
      const float* mrow_ = mask + (size_t)qrow * S_LEN + kv0abs;                              \
      _Pragma("unroll")                                                                       \
      for (int r = 0; r < 16; ++r) {                                                          \
        int key = (r & 3) + 8 * (r >> 2) + 4 * l5;                                            \
        if (mrow_[key] < 0.1f) sA[r] = -1e30f;                                                \
        if (mrow_[key + 32] < 0.1f) sB[r] = -1e30f;                                           \
      }                                                                                       \
    }                                                                                         \
    float pm = m_run;                                                                         \
    _Pragma("unroll")                                                                         \
    for (int r = 0; r < 16; ++r) pm = fmaxf(pm, fmaxf(sA[r], sB[r]));                         \
    pm = fmaxf(pm, __shfl_xor(pm, 32, 64));                                                   \
    if (!__all(pm <= m_run + 8.f)) {                                                          \
      float corr = __builtin_amdgcn_exp2f(m_run - pm);                                        \
      m_run = pm;                                                                             \
      l_run *= corr;                                                                          \
      _Pragma("unroll")                                                                       \
      for (int r = 0; r < 16; ++r) { oA[r] *= corr; oB[r] *= corr; }                          \
    }                                                                                         \
    float ps = 0.f;                                                                           \
    _Pragma("unroll")                                                                         \
    for (int r = 0; r < 16; ++r) {                                                            \
      sA[r] = __builtin_amdgcn_exp2f(sA[r] - m_run);                                          \
      sB[r] = __builtin_amdgcn_exp2f(sB[r] - m_run);                                          \
      ps += sA[r] + sB[r];                                                                    \
    }                                                                                         \
    l_run += ps;                                                                              \
    _Pragma("unroll")                                                                         \
    for (int kh = 0; kh < 2; ++kh) {                                                          \
      f32x16 s_ = kh ? sB : sA;                                                               \
      _Pragma("unroll")                                                                       \
      for (int c = 0; c < 2; ++c) {                                                           \
        int base = c * 8;                                                                     \
        unsigned u0 = cvtpk_bf16(s_[base + 0], s_[base + 1]);                                 \
        unsigned u1 = cvtpk_bf16(s_[base + 2], s_[base + 3]);                                 \
        unsigned u2 = cvtpk_bf16(s_[base + 4], s_[base + 5]);                                 \
        unsigned u3 = cvtpk_bf16(s_[base + 6], s_[base + 7]);                                 \
        asm volatile("v_permlane32_swap_b32 %0, %1" : "+v"(u0), "+v"(u2));                    \
        asm volatile("v_permlane32_swap_b32 %0, %1" : "+v"(u1), "+v"(u3));                    \
        int32x4 wds = {(int)u0, (int)u1, (int)u2, (int)u3};                                   \
        bf16x8 pb = *(bf16x8*)&wds;                                                           \
        int kslot = (kh * 2 + c) * 2 + l5;                                                    \
        int vr0 = l31, vr1 = 32 + l31;                                                        \
        bf16x8 va0 = *(const bf16x8*)&Vs[CUR][vr0 * 64 + (kslot ^ (vr0 & 7)) * 8];            \
        bf16x8 va1 = *(const bf16x8*)&Vs[CUR][vr1 * 64 + (kslot ^ (vr1 & 7)) * 8];            \
        oA = __builtin_amdgcn_mfma_f32_32x32x16_bf16(va0, pb, oA, 0, 0, 0);                   \
        oB = __builtin_amdgcn_mfma_f32_32x32x16_bf16(va1, pb, oB, 0, 0, 0);                   \
      }                                                                                       \
    }                                                                                         \
  } while (0)

  for (int tt = 0; tt < 8; ++tt) {
    ATTN_TILE(2 * tt, 0);
    ATTN_TILE(2 * tt + 1, 1);
  }
#undef ATTN_TILE

  float l_tot = l_run + __shfl_xor(l_run, 32, 64);
  // unnormalized O-half + (m, l)
  u16* op = Oh + (((size_t)hf * 32 + bh) * S_LEN + qrow) * 64;
  #pragma unroll
  for (int db = 0; db < 2; ++db) {
    f32x16 o = db ? oB : oA;
    #pragma unroll
    for (int g = 0; g < 4; ++g) {
      int d0 = db * 32 + 8 * g + 4 * l5;
      ushort4 st;
      st.x = f2bf(o[4 * g + 0]);
      st.y = f2bf(o[4 * g + 1]);
      st.z = f2bf(o[4 * g + 2]);
      st.w = f2bf(o[4 * g + 3]);
      *(ushort4*)(op + d0) = st;
    }
  }
  if (lane < 32) ml[((size_t)hf * 32 + bh) * S_LEN + qrow] = make_float2(m_run, l_tot);
}

// ---------- merge the two KV halves: O = (O0*w0 + O1*w1) / (l0*w0 + l1*w1) ----------
__global__ __launch_bounds__(256) void k_attn_merge(const u16* __restrict__ Oh,
                                                    const float2* __restrict__ ml,
                                                    u16* __restrict__ Out) {
  int idx = blockIdx.x * 256 + threadIdx.x;  // 32*2048*8
  int d8 = idx & 7;
  int q = (idx >> 3) & 2047;
  int bh = idx >> 14;
  float2 a = ml[(size_t)bh * S_LEN + q];
  float2 b = ml[(size_t)(32 + bh) * S_LEN + q];
  float m = fmaxf(a.x, b.x);
  float w0 = __builtin_amdgcn_exp2f(a.x - m);
  float w1 = __builtin_amdgcn_exp2f(b.x - m);
  float inv = 1.f / (a.y * w0 + b.y * w1);
  w0 *= inv; w1 *= inv;
  const ushort4* p0 = (const ushort4*)(Oh + ((size_t)bh * S_LEN + q) * 64 + d8 * 8);
  const ushort4* p1 = (const ushort4*)(Oh + ((size_t)(32 + bh) * S_LEN + q) * 64 + d8 * 8);
  ushort4 x0 = p0[0], x1 = p0[1];
  ushort4 y0 = p1[0], y1 = p1[1];
  int bb = bh >> 4, h = bh & 15;
  int mrow = q * 2 + bb;
  ushort4 o0, o1;
  o0.x = f2bf(bf2f(x0.x) * w0 + bf2f(y0.x) * w1);
  o0.y = f2bf(bf2f(x0.y) * w0 + bf2f(y0.y) * w1);
  o0.z = f2bf(bf2f(x0.z) * w0 + bf2f(y0.z) * w1);
  o0.w = f2bf(bf2f(x0.w) * w0 + bf2f(y0.w) * w1);
  o1.x = f2bf(bf2f(x1.x) * w0 + bf2f(y1.x) * w1);
  o1.y = f2bf(bf2f(x1.y) * w0 + bf2f(y1.y) * w1);
  o1.z = f2bf(bf2f(x1.z) * w0 + bf2f(y1.z) * w1);
  o1.w = f2bf(bf2f(x1.w) * w0 + bf2f(y1.w) * w1);
  u16* op = Out + (size_t)mrow * DM + h * 64 + d8 * 8;
  *(ushort4*)op = o0;
  *(ushort4*)(op + 4) = o1;
}

// ---------- fused LayerNorm: x = addf + bvec + sum of 4 bf16 partials; LN -> Yf (+Yb) ----------
__device__ __forceinline__ float wave_sum(float v) {
  #pragma unroll
  for (int off = 32; off >= 1; off >>= 1) v += __shfl_xor(v, off, 64);
  return v;
}

template <int WB>
__global__ __launch_bounds__(256) void k_lnp(const u16* __restrict__ pb, const float* __restrict__ addf,
                                             const float* __restrict__ bvec,
                                             const float* __restrict__ gw, const float* __restrict__ bw,
                                             float* __restrict__ Yf, u16* __restrict__ Yb) {
  int m = blockIdx.x;
  int tid = threadIdx.x, lane = tid & 63, w = tid >> 6;
  __shared__ float part[4];
  __shared__ float shv[2];
  float4 sc = ((const float4*)(addf + (size_t)m * DM))[tid];
  float4 bv = ((const float4*)bvec)[tid];
  float vx = sc.x + bv.x, vy = sc.y + bv.y, vz = sc.z + bv.z, vw = sc.w + bv.w;
  #pragma unroll
  for (int z = 0; z < 4; ++z) {
    ushort4 qv = ((const ushort4*)(pb + (size_t)z * MROWS * DM + (size_t)m * DM))[tid];
    vx += bf2f(qv.x); vy += bf2f(qv.y); vz += bf2f(qv.z); vw += bf2f(qv.w);
  }
  float s = wave_sum(vx + vy + vz + vw);
  if (lane == 0) part[w] = s;
  __syncthreads();
  if (tid == 0) shv[0] = (part[0] + part[1] + part[2] + part[3]) * (1.f / DM);
  __syncthreads();
  float mu = shv[0];
  float d0 = vx - mu, d1 = vy - mu, d2 = vz - mu, d3 = vw - mu;
  float q = wave_sum(d0 * d0 + d1 * d1 + d2 * d2 + d3 * d3);
  if (lane == 0) part[w] = q;
  __syncthreads();
  if (tid == 0) shv[1] = rsqrtf((part[0] + part[1] + part[2] + part[3]) * (1.f / DM) + 1e-5f);
  __syncthreads();
  float rstd = shv[1];
  float4 g4 = ((const float4*)gw)[tid];
  float4 b4 = ((const float4*)bw)[tid];
  float y0 = d0 * rstd * g4.x + b4.x;
  float y1 = d1 * rstd * g4.y + b4.y;
  float y2 = d2 * rstd * g4.z + b4.z;
  float y3 = d3 * rstd * g4.w + b4.w;
  ((float4*)(Yf + (size_t)m * DM))[tid] = make_float4(y0, y1, y2, y3);
  if (WB) {
    ushort4 o;
    o.x = f2bf(y0); o.y = f2bf(y1); o.z = f2bf(y2); o.w = f2bf(y3);
    ((ushort4*)(Yb + (size_t)m * DM))[tid] = o;
  }
}

extern "C" void kernel_launch(void* const* d_in, const int* in_sizes, int n_in,
                              void* d_out, int out_size, void* d_ws, size_t ws_size,
                              hipStream_t stream) {
  (void)in_sizes; (void)n_in; (void)out_size; (void)ws_size;
  const float* src  = (const float*)d_in[0];
  const float* mask = (const float*)d_in[1];
  const float* Wq = (const float*)d_in[2];  const float* bq  = (const float*)d_in[3];
  const float* Wk = (const float*)d_in[4];  const float* bk  = (const float*)d_in[5];
  const float* Wv = (const float*)d_in[6];  const float* bv  = (const float*)d_in[7];
  const float* Wo = (const float*)d_in[8];  const float* bo  = (const float*)d_in[9];
  const float* W1 = (const float*)d_in[10]; const float* b1  = (const float*)d_in[11];
  const float* W2 = (const float*)d_in[12]; const float* b2  = (const float*)d_in[13];
  const float* g1 = (const float*)d_in[14]; const float* be1 = (const float*)d_in[15];
  const float* g2 = (const float*)d_in[16]; const float* be2 = (const float*)d_in[17];
  float* out = (float*)d_out;

  char* base = (char*)d_ws;
  size_t off = 0;
  auto carve = [&](size_t bytes) -> void* {
    void* r = base + off;
    off += (bytes + 255) & ~(size_t)255;
    return r;
  };
  u16* Wq_t = (u16*)carve(2ull * 1024 * 1024);  // Wq_t/Wk_t/Wv_t contiguous -> fused N=3072 GEMM
  u16* Wk_t = (u16*)carve(2ull * 1024 * 1024);
  u16* Wv_t = (u16*)carve(2ull * 1024 * 1024);
  u16* Wo_t = (u16*)carve(2ull * 1024 * 1024);
  u16* W1_t = (u16*)carve(2ull * 4096 * 1024);
  u16* W2_t = (u16*)carve(2ull * 1024 * 4096);
  u16* Xbf  = (u16*)carve(2ull * 4096 * 1024);
  float* cosT = (float*)carve(4ull * 2048 * 32);
  float* sinT = (float*)carve(4ull * 2048 * 32);
  float* bqkv = (float*)carve(4ull * 3072);
  unsigned char* mflags = (unsigned char*)carve(1024);
  u16* attn_out = (u16*)carve(2ull * 4096 * 1024);
  float* src2f = (float*)carve(4ull * 4096 * 1024);     // dedicated: live LN1 -> LN2
  float* QKV = (float*)carve(4ull * 4096 * 3072);       // 48MB region, multiply reused
  u16* Qh = (u16*)carve(2ull * 32 * 2048 * 64);         // 8MB
  u16* Kh = (u16*)carve(2ull * 32 * 2048 * 64);         // 8MB
  u16* Vt = (u16*)carve(2ull * 32 * 2048 * 64);         // 8MB
  // Aliases (lifetimes):
  //   QKVb = QKV region as bf16 (24MB): dead after rope_heads.
  //   Oh   = QKV+0 (17MB: 2halves x 32bh x 2048 x 64 bf16) + ml at QKV+18MB (1MB):
  //          written by attn, consumed by merge; dead before Wo GEMM writes woPb.
  //   woPb = QKV+0 (4 x 8MB bf16): Wo split-K=4 partials, consumed by LN1.
  //   ff1  = QKV+0 (32MB bf16): written by FF1 after LN1 (woPb dead).
  //   ffPb = QKV+32MB..+64MB (4 x 8MB bf16): FF2 partials; spans QKV tail + Qh + Kh
  //          (Qh/Kh dead after attn+merge). Consumed by LN2.
  //   src2b = Vt (8MB bf16): Vt dead after attn; consumed by FF1.
  u16* QKVb = (u16*)QKV;
  u16* Oh   = (u16*)QKV;
  float2* mlbuf = (float2*)((char*)QKV + 18ull * 1024 * 1024);
  u16* woPb = (u16*)QKV;
  u16* ff1 = (u16*)QKV;
  u16* ffPb = (u16*)((char*)QKV + 32ull * 1024 * 1024);
  u16* src2b = (u16*)Vt;

  dim3 blk(256);
  dim3 blk5(512);
  k_transpose4<<<dim3(32, 32, 4), blk, 0, stream>>>(Wq, Wk, Wv, Wo, Wq_t, Wk_t, Wv_t, Wo_t);
  k_transpose_bf16<<<dim3(128, 32), blk, 0, stream>>>(W1, W1_t, 1024, 4096);
  k_transpose_bf16<<<dim3(32, 128), blk, 0, stream>>>(W2, W2_t, 4096, 1024);
  k_f2bf4<<<dim3(4096), blk, 0, stream>>>((const float4*)src, (ushort4*)Xbf, 4096 * 1024 / 4);
  k_rope_table<<<dim3(256), blk, 0, stream>>>(cosT, sinT);
  k_cat3<<<dim3(12), blk, 0, stream>>>(bq, bk, bv, bqkv);
  k_mask_flags<<<dim3(32, 32), blk, 0, stream>>>(mask, mflags);
  // fused QKV projection (M=4096, N=3072, K=1024) -> bf16
  k_gemm256<EPI_BF16><<<dim3(12, 16, 1), blk5, 0, stream>>>(Xbf, Wq_t, bqkv, nullptr, QKVb, 4096, 3072, 1024, 3072, 1024);
  k_rope_heads<<<dim3(MROWS * 512 / 256), blk, 0, stream>>>(QKVb, cosT, sinT, Qh, Kh, Vt);
  // attention: KV-split-2, 1024 blocks, 4 blocks/CU
  k_attn<<<dim3(32, 32), blk, 0, stream>>>(Qh, Kh, Vt, mask, mflags, Oh, mlbuf);
  k_attn_merge<<<dim3(32 * 2048 * 8 / 256), blk, 0, stream>>>(Oh, mlbuf, attn_out);
  // O-projection: split-K=4, bf16 partials -> LN1
  k_gemm256<EPI_PARTB><<<dim3(4, 16, 4), blk5, 0, stream>>>(attn_out, Wo_t, nullptr, nullptr, woPb, 4096, 1024, 1024, 1024, 256);
  k_lnp<1><<<dim3(4096), blk, 0, stream>>>(woPb, src, bo, g1, be1, src2f, src2b);
  // FF1 with ReLU
  k_gemm256<EPI_RELU_BF16><<<dim3(16, 16, 1), blk5, 0, stream>>>(src2b, W1_t, b1, nullptr, ff1, 4096, 4096, 1024, 4096, 1024);
  // FF2: split-K=4, bf16 partials -> LN2
  k_gemm256<EPI_PARTB><<<dim3(4, 16, 4), blk5, 0, stream>>>(ff1, W2_t, nullptr, nullptr, ffPb, 4096, 1024, 4096, 1024, 1024);
  k_lnp<0><<<dim3(4096), blk, 0, stream>>>(ffPb, src2f, b2, g2, be2, out, nullptr);
}

// Round 9
// 329.412 us; speedup vs baseline: 1.0508x; 1.0508x over previous
//
#include <hip/hip_runtime.h>
#include <math.h>

#define S_LEN 2048
#define DM 1024
#define NH 16
#define HD 64
#define DFF 4096
#define MROWS 4096  // S_LEN * 2 batch

typedef unsigned short u16;
typedef __attribute__((ext_vector_type(8))) __bf16 bf16x8;
typedef __attribute__((ext_vector_type(4))) float f32x4;
typedef __attribute__((ext_vector_type(16))) float f32x16;
typedef __attribute__((ext_vector_type(4))) int int32x4;

__device__ __forceinline__ u16 f2bf(float f) {
  unsigned u = __float_as_uint(f);
  unsigned r = (u + 0x7fffu + ((u >> 16) & 1u)) >> 16;  // RNE
  return (u16)r;
}

__device__ __forceinline__ float bf2f(u16 u) {
  return __uint_as_float((unsigned)u << 16);
}

__device__ __forceinline__ unsigned cvtpk_bf16(float lo, float hi) {
  unsigned r;
  asm("v_cvt_pk_bf16_f32 %0, %1, %2" : "=v"(r) : "v"(lo), "v"(hi));
  return r;
}

__device__ __forceinline__ void gload_lds16(const void* g, void* l) {
  __builtin_amdgcn_global_load_lds((__attribute__((address_space(1))) void*)g,
                                   (__attribute__((address_space(3))) void*)l, 16, 0, 0);
}

// ---------- 4x fused transpose + fp32->bf16 weights (1024x1024): W -> Wt ----------
__global__ __launch_bounds__(256) void k_transpose4(const float* __restrict__ W0, const float* __restrict__ W1,
                                                    const float* __restrict__ W2, const float* __restrict__ W3,
                                                    u16* __restrict__ T0, u16* __restrict__ T1,
                                                    u16* __restrict__ T2, u16* __restrict__ T3) {
  __shared__ float tile[32][33];
  const float* W = blockIdx.z == 0 ? W0 : blockIdx.z == 1 ? W1 : blockIdx.z == 2 ? W2 : W3;
  u16* Wt = blockIdx.z == 0 ? T0 : blockIdx.z == 1 ? T1 : blockIdx.z == 2 ? T2 : T3;
  int n0 = blockIdx.x * 32, k0 = blockIdx.y * 32;
  int tx = threadIdx.x & 31, ty = threadIdx.x >> 5;
  #pragma unroll
  for (int r = ty; r < 32; r += 8) tile[r][tx] = W[(size_t)(k0 + r) * 1024 + n0 + tx];
  __syncthreads();
  #pragma unroll
  for (int r = ty; r < 32; r += 8) Wt[(size_t)(n0 + r) * 1024 + k0 + tx] = f2bf(tile[tx][r]);
}

__global__ __launch_bounds__(256) void k_transpose_bf16(const float* __restrict__ W,
                                                        u16* __restrict__ Wt, int K, int N) {
  __shared__ float tile[32][33];
  int n0 = blockIdx.x * 32, k0 = blockIdx.y * 32;
  int tx = threadIdx.x & 31, ty = threadIdx.x >> 5;
  #pragma unroll
  for (int r = ty; r < 32; r += 8) tile[r][tx] = W[(size_t)(k0 + r) * N + n0 + tx];
  __syncthreads();
  #pragma unroll
  for (int r = ty; r < 32; r += 8) Wt[(size_t)(n0 + r) * K + k0 + tx] = f2bf(tile[tx][r]);
}

__global__ __launch_bounds__(256) void k_f2bf4(const float4* __restrict__ in,
                                               ushort4* __restrict__ out, int n4) {
  int i = blockIdx.x * 256 + threadIdx.x;
  if (i >= n4) return;
  float4 v = in[i];
  ushort4 o;
  o.x = f2bf(v.x); o.y = f2bf(v.y); o.z = f2bf(v.z); o.w = f2bf(v.w);
  out[i] = o;
}

__global__ __launch_bounds__(256) void k_rope_table(float* __restrict__ cosT,
                                                    float* __restrict__ sinT) {
  int idx = blockIdx.x * 256 + threadIdx.x;
  if (idx >= S_LEN * 32) return;
  int s = idx >> 5, i = idx & 31;
  float inv = powf(10000.f, -(float)(2 * i) / 64.f);
  float ang = (float)s * inv;
  cosT[idx] = cosf(ang);
  sinT[idx] = sinf(ang);
}

__global__ __launch_bounds__(256) void k_cat3(const float* __restrict__ a, const float* __restrict__ b,
                                              const float* __restrict__ c, float* __restrict__ o) {
  int i = blockIdx.x * 256 + threadIdx.x;
  if (i >= 3072) return;
  o[i] = i < 1024 ? a[i] : (i < 2048 ? b[i - 1024] : c[i - 2048]);
}

// ---------- mask tile flags: 0 = all pass (>=0.1), 1 = mixed/masked ----------
__global__ __launch_bounds__(256) void k_mask_flags(const float* __restrict__ mask,
                                                    unsigned char* __restrict__ flags) {
  int kt = blockIdx.x, qt = blockIdx.y;
  const float* mp = mask + (size_t)(qt * 64) * S_LEN + kt * 64;
  int tr = threadIdx.x >> 2;
  int tc = (threadIdx.x & 3) * 16;
  int ok = 1;
  #pragma unroll
  for (int c = 0; c < 16; c += 4) {
    float4 v = *(const float4*)(mp + (size_t)tr * S_LEN + tc + c);
    ok &= (v.x >= 0.1f) & (v.y >= 0.1f) & (v.z >= 0.1f) & (v.w >= 0.1f);
  }
  ok = __all(ok) ? 1 : 0;
  __shared__ int sh[4];
  if ((threadIdx.x & 63) == 0) sh[threadIdx.x >> 6] = ok;
  __syncthreads();
  if (threadIdx.x == 0) flags[qt * 32 + kt] = (sh[0] & sh[1] & sh[2] & sh[3]) ? 0 : 1;
}

// ---------- 256x256-tile pipelined bf16 GEMM ----------
enum { EPI_F32 = 0, EPI_RELU_BF16 = 2, EPI_PARTB = 4, EPI_BF16 = 5 };

template <int EPI>
__global__ __launch_bounds__(512, 2) void k_gemm256(const u16* __restrict__ A,
                                                    const u16* __restrict__ Bt,
                                                    const float* __restrict__ bias,
                                                    float* __restrict__ Cf, u16* __restrict__ Cb,
                                                    int M, int N, int K, int ldc, int Kc) {
  __shared__ __attribute__((aligned(16))) u16 As[4][256 * 32];
  __shared__ __attribute__((aligned(16))) u16 Bs[4][256 * 32];

  int nx = gridDim.x;
  int nwg = nx * gridDim.y;
  int flat = blockIdx.y * nx + blockIdx.x;
  int id = (flat & 7) * (nwg >> 3) + (flat >> 3);
  int n0 = (id % nx) * 256;
  int m0 = (id / nx) * 256;
  int kz = blockIdx.z * Kc;

  int tid = threadIdx.x;
  int lane = tid & 63, w = tid >> 6;
  int wm = (w >> 2) * 128, wn = (w & 3) * 64;
  int l15 = lane & 15, l4 = lane >> 4;
  int NT = Kc >> 5;

  const u16* aS[2];
  const u16* bS[2];
  int dslot[2];
  #pragma unroll
  for (int j = 0; j < 2; ++j) {
    int P = j * 512 + tid;
    int r = P >> 2;
    int sl = (P & 3) ^ (r & 3);
    aS[j] = A + (size_t)(m0 + r) * K + kz + sl * 8;
    bS[j] = Bt + (size_t)(n0 + r) * K + kz + sl * 8;
    dslot[j] = j * 512 + w * 64;
  }

  f32x4 acc[8][4] = {};

  #pragma unroll
  for (int t = 0; t < 3; ++t) {
    #pragma unroll
    for (int j = 0; j < 2; ++j) {
      gload_lds16(aS[j] + t * 32, &As[t][dslot[j] * 8]);
      gload_lds16(bS[j] + t * 32, &Bs[t][dslot[j] * 8]);
    }
  }

  for (int t = 0; t < NT; ++t) {
    int buf = t & 3;
    if (t < NT - 2) asm volatile("s_waitcnt vmcnt(8)" ::: "memory");
    else if (t == NT - 2) asm volatile("s_waitcnt vmcnt(4)" ::: "memory");
    else asm volatile("s_waitcnt vmcnt(0)" ::: "memory");
    __builtin_amdgcn_s_barrier();

    if (t + 3 < NT) {
      int tn = t + 3;
      int bn = tn & 3;
      #pragma unroll
      for (int j = 0; j < 2; ++j) {
        gload_lds16(aS[j] + tn * 32, &As[bn][dslot[j] * 8]);
        gload_lds16(bS[j] + tn * 32, &Bs[bn][dslot[j] * 8]);
      }
    }

    bf16x8 af[8], bq[4];
    #pragma unroll
    for (int m = 0; m < 8; ++m) {
      int r = wm + m * 16 + l15;
      af[m] = *(const bf16x8*)&As[buf][r * 32 + (l4 ^ (r & 3)) * 8];
    }
    #pragma unroll
    for (int n = 0; n < 4; ++n) {
      int r = wn + n * 16 + l15;
      bq[n] = *(const bf16x8*)&Bs[buf][r * 32 + (l4 ^ (r & 3)) * 8];
    }
    __builtin_amdgcn_s_setprio(1);
    #pragma unroll
    for (int m = 0; m < 8; ++m)
      #pragma unroll
      for (int n = 0; n < 4; ++n)
        acc[m][n] = __builtin_amdgcn_mfma_f32_16x16x32_bf16(af[m], bq[n], acc[m][n], 0, 0, 0);
    __builtin_amdgcn_s_setprio(0);
  }

  size_t zoff = (size_t)blockIdx.z * M * ldc;
  #pragma unroll
  for (int m = 0; m < 8; ++m) {
    #pragma unroll
    for (int n = 0; n < 4; ++n) {
      int col = n0 + wn + n * 16 + l15;
      float bv = (EPI == EPI_PARTB) ? 0.f : bias[col];
      #pragma unroll
      for (int r = 0; r < 4; ++r) {
        int row = m0 + wm + m * 16 + l4 * 4 + r;
        float v = acc[m][n][r] + bv;
        size_t o = (size_t)row * ldc + col;
        if (EPI == EPI_F32) Cf[o] = v;
        else if (EPI == EPI_RELU_BF16) Cb[o] = f2bf(fmaxf(v, 0.f));
        else if (EPI == EPI_BF16) Cb[o] = f2bf(v);
        else Cb[zoff + o] = f2bf(v);
      }
    }
  }
}

// ---------- RoPE + head-split (bf16 QKV in); Q pre-scaled by log2(e)/sqrt(HD) ----------
#define QSCALE 0.180336881f
__global__ __launch_bounds__(256) void k_rope_heads(const u16* __restrict__ QKVb,
                                                    const float* __restrict__ cosT,
                                                    const float* __restrict__ sinT,
                                                    u16* __restrict__ Qh, u16* __restrict__ Kh,
                                                    u16* __restrict__ Vt) {
  int idx = blockIdx.x * 256 + threadIdx.x;
  if (idx >= MROWS * 512) return;
  int m = idx >> 9, c2 = idx & 511;
  int h = c2 >> 5, i = c2 & 31, d = 2 * i;
  int s = m >> 1, b = m & 1;
  int bh = b * NH + h;
  size_t base = (size_t)m * 3072 + h * 64 + d;
  float q0 = bf2f(QKVb[base]), q1 = bf2f(QKVb[base + 1]);
  float k0 = bf2f(QKVb[base + 1024]), k1 = bf2f(QKVb[base + 1025]);
  float v0 = bf2f(QKVb[base + 2048]), v1 = bf2f(QKVb[base + 2049]);
  float c = cosT[s * 32 + i], sn = sinT[s * 32 + i];
  size_t ho = ((size_t)bh * S_LEN + s) * 64 + d;
  Qh[ho]     = f2bf((q0 * c - q1 * sn) * QSCALE);
  Qh[ho + 1] = f2bf((q1 * c + q0 * sn) * QSCALE);
  Kh[ho]     = f2bf(k0 * c - k1 * sn);
  Kh[ho + 1] = f2bf(k1 * c + k0 * sn);
  size_t vo = ((size_t)bh * 64 + d) * S_LEN + s;
  Vt[vo] = f2bf(v0);
  Vt[vo + S_LEN] = f2bf(v1);
}

// ---------- flash attention: 8 waves = 4 q-groups x 2 kv-halves, swapped-QK^T 32x32x16,
//            in-register softmax, double-buffered 128-key tiles, end-of-block LSE merge ----------
__global__ __launch_bounds__(512, 4) void k_attn(const u16* __restrict__ Qh, const u16* __restrict__ Kh,
                                                 const u16* __restrict__ Vt,
                                                 const float* __restrict__ mask,
                                                 const unsigned char* __restrict__ flags,
                                                 u16* __restrict__ Out) {
  __shared__ __attribute__((aligned(16))) u16 Ks[2][128 * 64];  // 32 KB (reused as O-exchange)
  __shared__ __attribute__((aligned(16))) u16 Vs[2][64 * 128];  // 32 KB (reused as m/l exchange)
  // XCD swizzle: flat id f -> xcd = f&7 owns heads [xcd*4, xcd*4+4)
  int f = blockIdx.y * gridDim.x + blockIdx.x;  // grid (16, 32)
  int xcd = f & 7, ii = f >> 3;
  int bh = xcd * 4 + (ii >> 4);
  int q0 = (ii & 15) * 128;
  int b = bh >> 4, h = bh & 15;
  int tid = threadIdx.x, lane = tid & 63, w = tid >> 6;
  int wq = w & 3, wh = w >> 2;  // q-group, kv-half
  int l31 = lane & 31, l5 = lane >> 5;

  int qrow = q0 + wq * 32 + l31;
  int qt = qrow >> 6;  // wave-uniform

  bf16x8 qf[4];
  {
    const u16* qp = Qh + ((size_t)bh * S_LEN + qrow) * 64 + l5 * 8;
    #pragma unroll
    for (int dc = 0; dc < 4; ++dc) qf[dc] = *(const bf16x8*)(qp + dc * 16);
  }

  const u16* Kbase = Kh + (size_t)bh * S_LEN * 64;
  const u16* Vbase = Vt + (size_t)bh * 64 * S_LEN;

  // staging: 512 threads x 2 slots each for K and V (per-lane invariant offsets)
  int koff_[2], voff_[2];
  #pragma unroll
  for (int i = 0; i < 2; ++i) {
    int s = i * 512 + tid;           // 16B slot in [0,1024)
    int kr = s >> 3, kslot = s & 7;
    koff_[i] = kr * 64 + (kslot ^ (kr & 7)) * 8;
    int vr = s >> 4, vslot = s & 15;
    voff_[i] = vr * S_LEN + (vslot ^ (vr & 15)) * 8;
  }

  float m_run = -1e30f, l_run = 0.f;
  f32x16 oA = {}, oB = {};

  // prologue: stage tile 0 -> buf 0
  #pragma unroll
  for (int i = 0; i < 2; ++i) {
    gload_lds16(Kbase + koff_[i], &Ks[0][(i * 512 + tid) * 8]);
    gload_lds16(Vbase + voff_[i], &Vs[0][(i * 512 + tid) * 8]);
  }

  int khalf = wh * 64;  // this wave's 64-key half within the 128-key tile

#define ATTN_TILE(T, CUR)                                                                     \
  do {                                                                                        \
    asm volatile("s_waitcnt vmcnt(0)" ::: "memory");                                          \
    __builtin_amdgcn_s_barrier();                                                             \
    if ((T) + 1 < 16) {                                                                       \
      const u16* kt_ = Kbase + (size_t)((T) + 1) * 8192;                                      \
      const u16* vt_ = Vbase + ((T) + 1) * 128;                                               \
      _Pragma("unroll")                                                                       \
      for (int i = 0; i < 2; ++i) {                                                           \
        gload_lds16(kt_ + koff_[i], &Ks[(CUR) ^ 1][(i * 512 + tid) * 8]);                     \
        gload_lds16(vt_ + voff_[i], &Vs[(CUR) ^ 1][(i * 512 + tid) * 8]);                     \
      }                                                                                       \
    }                                                                                         \
    f32x16 sA = {}, sB = {};                                                                  \
    _Pragma("unroll")                                                                         \
    for (int dc = 0; dc < 4; ++dc) {                                                          \
      int r0 = khalf + l31, r1 = khalf + 32 + l31;                                            \
      int slot = (dc * 2 + l5) ^ (l31 & 7);                                                   \
      bf16x8 ka0 = *(const bf16x8*)&Ks[CUR][r0 * 64 + slot * 8];                              \
      bf16x8 ka1 = *(const bf16x8*)&Ks[CUR][r1 * 64 + slot * 8];                              \
      sA = __builtin_amdgcn_mfma_f32_32x32x16_bf16(ka0, qf[dc], sA, 0, 0, 0);                 \
      sB = __builtin_amdgcn_mfma_f32_32x32x16_bf16(ka1, qf[dc], sB, 0, 0, 0);                 \
    }                                                                                         \
    int kv0abs = (T) * 128 + khalf;                                                           \
    int fl = flags[qt * 32 + (kv0abs >> 6)];                                                  \
    if (fl) {                                                                                 \
      const float* mrow_ = mask + (size_t)qrow * S_LEN + kv0abs;                              \
      _Pragma("unroll")                                                                       \
      for (int r = 0; r < 16; ++r) {                                                          \
        int key = (r & 3) + 8 * (r >> 2) + 4 * l5;                                            \
        if (mrow_[key] < 0.1f) sA[r] = -1e30f;                                                \
        if (mrow_[key + 32] < 0.1f) sB[r] = -1e30f;                                           \
      }                                                                                       \
    }                                                                                         \
    float pm = m_run;                                                                         \
    _Pragma("unroll")                                                                         \
    for (int r = 0; r < 16; ++r) pm = fmaxf(pm, fmaxf(sA[r], sB[r]));                         \
    pm = fmaxf(pm, __shfl_xor(pm, 32, 64));                                                   \
    if (!__all(pm <= m_run + 8.f)) {                                                          \
      float corr = __builtin_amdgcn_exp2f(m_run - pm);                                        \
      m_run = pm;                                                                             \
      l_run *= corr;                                                                          \
      _Pragma("unroll")                                                                       \
      for (int r = 0; r < 16; ++r) { oA[r] *= corr; oB[r] *= corr; }                          \
    }                                                                                         \
    float ps = 0.f;                                                                           \
    _Pragma("unroll")                                                                         \
    for (int r = 0; r < 16; ++r) {                                                            \
      sA[r] = __builtin_amdgcn_exp2f(sA[r] - m_run);                                          \
      sB[r] = __builtin_amdgcn_exp2f(sB[r] - m_run);                                          \
      ps += sA[r] + sB[r];                                                                    \
    }                                                                                         \
    l_run += ps;                                                                              \
    _Pragma("unroll")                                                                         \
    for (int kh = 0; kh < 2; ++kh) {                                                          \
      f32x16 s_ = kh ? sB : sA;                                                               \
      _Pragma("unroll")                                                                       \
      for (int c = 0; c < 2; ++c) {                                                           \
        int base = c * 8;                                                                     \
        unsigned u0 = cvtpk_bf16(s_[base + 0], s_[base + 1]);                                 \
        unsigned u1 = cvtpk_bf16(s_[base + 2], s_[base + 3]);                                 \
        unsigned u2 = cvtpk_bf16(s_[base + 4], s_[base + 5]);                                 \
        unsigned u3 = cvtpk_bf16(s_[base + 6], s_[base + 7]);                                 \
        asm volatile("v_permlane32_swap_b32 %0, %1" : "+v"(u0), "+v"(u2));                    \
        asm volatile("v_permlane32_swap_b32 %0, %1" : "+v"(u1), "+v"(u3));                    \
        int32x4 wds = {(int)u0, (int)u1, (int)u2, (int)u3};                                   \
        bf16x8 pb = *(bf16x8*)&wds;                                                           \
        int kslot = wh * 8 + (kh * 2 + c) * 2 + l5;                                           \
        int vr0 = l31, vr1 = 32 + l31;                                                        \
        bf16x8 va0 = *(const bf16x8*)&Vs[CUR][vr0 * 128 + (kslot ^ (vr0 & 15)) * 8];          \
        bf16x8 va1 = *(const bf16x8*)&Vs[CUR][vr1 * 128 + (kslot ^ (vr1 & 15)) * 8];          \
        oA = __builtin_amdgcn_mfma_f32_32x32x16_bf16(va0, pb, oA, 0, 0, 0);                   \
        oB = __builtin_amdgcn_mfma_f32_32x32x16_bf16(va1, pb, oB, 0, 0, 0);                   \
      }                                                                                       \
    }                                                                                         \
  } while (0)

  for (int tt = 0; tt < 8; ++tt) {
    ATTN_TILE(2 * tt, 0);
    ATTN_TILE(2 * tt + 1, 1);
  }
#undef ATTN_TILE

  // ---- end-of-block merge of the two kv-halves (waves w and w^4) ----
  float l_tot = l_run + __shfl_xor(l_run, 32, 64);
  __syncthreads();  // all compute done; LDS reusable
  float* mlds = (float*)Vs;  // [2][8 waves][64 lanes]
  mlds[w * 64 + lane] = m_run;
  mlds[512 + w * 64 + lane] = l_tot;
  __syncthreads();
  int pw = w ^ 4;
  float pm2 = mlds[pw * 64 + lane];
  float pl2 = mlds[512 + pw * 64 + lane];
  float M = fmaxf(m_run, pm2);
  float wgt = __builtin_amdgcn_exp2f(m_run - M);
  float pwgt = __builtin_amdgcn_exp2f(pm2 - M);
  float denom = l_tot * wgt + pl2 * pwgt;  // symmetric: both waves compute same value
  float* oxc = (float*)Ks;  // [32 regs][256 lanes] transposed -> conflict-free
  if (wh == 1) {
    #pragma unroll
    for (int r = 0; r < 16; ++r) {
      oxc[r * 256 + wq * 64 + lane] = oA[r] * wgt;
      oxc[(16 + r) * 256 + wq * 64 + lane] = oB[r] * wgt;
    }
  }
  __syncthreads();
  if (wh == 0) {
    float inv = 1.f / denom;
    int mrow = qrow * 2 + b;
    u16* op = Out + (size_t)mrow * DM + h * 64;
    #pragma unroll
    for (int db = 0; db < 2; ++db) {
      f32x16 o = db ? oB : oA;
      #pragma unroll
      for (int g = 0; g < 4; ++g) {
        int d0 = db * 32 + 8 * g + 4 * l5;
        ushort4 st;
        st.x = f2bf((o[4 * g + 0] * wgt + oxc[(db * 16 + 4 * g + 0) * 256 + wq * 64 + lane]) * inv);
        st.y = f2bf((o[4 * g + 1] * wgt + oxc[(db * 16 + 4 * g + 1) * 256 + wq * 64 + lane]) * inv);
        st.z = f2bf((o[4 * g + 2] * wgt + oxc[(db * 16 + 4 * g + 2) * 256 + wq * 64 + lane]) * inv);
        st.w = f2bf((o[4 * g + 3] * wgt + oxc[(db * 16 + 4 * g + 3) * 256 + wq * 64 + lane]) * inv);
        *(ushort4*)(op + d0) = st;
      }
    }
  }
}

// ---------- fused LayerNorm: x = addf + bvec + sum of 4 bf16 partials; LN -> Yf (+Yb) ----------
__device__ __forceinline__ float wave_sum(float v) {
  #pragma unroll
  for (int off = 32; off >= 1; off >>= 1) v += __shfl_xor(v, off, 64);
  return v;
}

template <int WB>
__global__ __launch_bounds__(256) void k_lnp(const u16* __restrict__ pb, const float* __restrict__ addf,
                                             const float* __restrict__ bvec,
                                             const float* __restrict__ gw, const float* __restrict__ bw,
                                             float* __restrict__ Yf, u16* __restrict__ Yb) {
  int m = blockIdx.x;
  int tid = threadIdx.x, lane = tid & 63, w = tid >> 6;
  __shared__ float part[4];
  __shared__ float shv[2];
  float4 sc = ((const float4*)(addf + (size_t)m * DM))[tid];
  float4 bv = ((const float4*)bvec)[tid];
  float vx = sc.x + bv.x, vy = sc.y + bv.y, vz = sc.z + bv.z, vw = sc.w + bv.w;
  #pragma unroll
  for (int z = 0; z < 4; ++z) {
    ushort4 qv = ((const ushort4*)(pb + (size_t)z * MROWS * DM + (size_t)m * DM))[tid];
    vx += bf2f(qv.x); vy += bf2f(qv.y); vz += bf2f(qv.z); vw += bf2f(qv.w);
  }
  float s = wave_sum(vx + vy + vz + vw);
  if (lane == 0) part[w] = s;
  __syncthreads();
  if (tid == 0) shv[0] = (part[0] + part[1] + part[2] + part[3]) * (1.f / DM);
  __syncthreads();
  float mu = shv[0];
  float d0 = vx - mu, d1 = vy - mu, d2 = vz - mu, d3 = vw - mu;
  float q = wave_sum(d0 * d0 + d1 * d1 + d2 * d2 + d3 * d3);
  if (lane == 0) part[w] = q;
  __syncthreads();
  if (tid == 0) shv[1] = rsqrtf((part[0] + part[1] + part[2] + part[3]) * (1.f / DM) + 1e-5f);
  __syncthreads();
  float rstd = shv[1];
  float4 g4 = ((const float4*)gw)[tid];
  float4 b4 = ((const float4*)bw)[tid];
  float y0 = d0 * rstd * g4.x + b4.x;
  float y1 = d1 * rstd * g4.y + b4.y;
  float y2 = d2 * rstd * g4.z + b4.z;
  float y3 = d3 * rstd * g4.w + b4.w;
  ((float4*)(Yf + (size_t)m * DM))[tid] = make_float4(y0, y1, y2, y3);
  if (WB) {
    ushort4 o;
    o.x = f2bf(y0); o.y = f2bf(y1); o.z = f2bf(y2); o.w = f2bf(y3);
    ((ushort4*)(Yb + (size_t)m * DM))[tid] = o;
  }
}

extern "C" void kernel_launch(void* const* d_in, const int* in_sizes, int n_in,
                              void* d_out, int out_size, void* d_ws, size_t ws_size,
                              hipStream_t stream) {
  (void)in_sizes; (void)n_in; (void)out_size; (void)ws_size;
  const float* src  = (const float*)d_in[0];
  const float* mask = (const float*)d_in[1];
  const float* Wq = (const float*)d_in[2];  const float* bq  = (const float*)d_in[3];
  const float* Wk = (const float*)d_in[4];  const float* bk  = (const float*)d_in[5];
  const float* Wv = (const float*)d_in[6];  const float* bv  = (const float*)d_in[7];
  const float* Wo = (const float*)d_in[8];  const float* bo  = (const float*)d_in[9];
  const float* W1 = (const float*)d_in[10]; const float* b1  = (const float*)d_in[11];
  const float* W2 = (const float*)d_in[12]; const float* b2  = (const float*)d_in[13];
  const float* g1 = (const float*)d_in[14]; const float* be1 = (const float*)d_in[15];
  const float* g2 = (const float*)d_in[16]; const float* be2 = (const float*)d_in[17];
  float* out = (float*)d_out;

  char* base = (char*)d_ws;
  size_t off = 0;
  auto carve = [&](size_t bytes) -> void* {
    void* r = base + off;
    off += (bytes + 255) & ~(size_t)255;
    return r;
  };
  u16* Wq_t = (u16*)carve(2ull * 1024 * 1024);  // Wq_t/Wk_t/Wv_t contiguous -> fused N=3072 GEMM
  u16* Wk_t = (u16*)carve(2ull * 1024 * 1024);
  u16* Wv_t = (u16*)carve(2ull * 1024 * 1024);
  u16* Wo_t = (u16*)carve(2ull * 1024 * 1024);
  u16* W1_t = (u16*)carve(2ull * 4096 * 1024);
  u16* W2_t = (u16*)carve(2ull * 1024 * 4096);
  u16* Xbf  = (u16*)carve(2ull * 4096 * 1024);
  float* cosT = (float*)carve(4ull * 2048 * 32);
  float* sinT = (float*)carve(4ull * 2048 * 32);
  float* bqkv = (float*)carve(4ull * 3072);
  unsigned char* mflags = (unsigned char*)carve(1024);
  u16* attn_out = (u16*)carve(2ull * 4096 * 1024);
  float* src2f = (float*)carve(4ull * 4096 * 1024);     // dedicated: live LN1 -> LN2
  float* QKV = (float*)carve(4ull * 4096 * 3072);       // 48MB region, multiply reused
  u16* Qh = (u16*)carve(2ull * 32 * 2048 * 64);         // 8MB
  u16* Kh = (u16*)carve(2ull * 32 * 2048 * 64);         // 8MB
  u16* Vt = (u16*)carve(2ull * 32 * 2048 * 64);         // 8MB
  // Aliases (lifetimes):
  //   QKVb = QKV region as bf16 (24MB): dead after rope_heads.
  //   woPb = QKV+0 (4 x 8MB bf16): Wo split-K=4 partials, consumed by LN1.
  //   ff1  = QKV+0 (32MB bf16): written by FF1 after LN1 (woPb dead).
  //   ffPb = QKV+32MB..+64MB (4 x 8MB bf16): FF2 partials; spans QKV tail + Qh + Kh
  //          (Qh/Kh dead after attn). Consumed by LN2.
  //   src2b = Vt (8MB bf16): Vt dead after attn; consumed by FF1.
  u16* QKVb = (u16*)QKV;
  u16* woPb = (u16*)QKV;
  u16* ff1 = (u16*)QKV;
  u16* ffPb = (u16*)((char*)QKV + 32ull * 1024 * 1024);
  u16* src2b = (u16*)Vt;

  dim3 blk(256);
  dim3 blk5(512);
  k_transpose4<<<dim3(32, 32, 4), blk, 0, stream>>>(Wq, Wk, Wv, Wo, Wq_t, Wk_t, Wv_t, Wo_t);
  k_transpose_bf16<<<dim3(128, 32), blk, 0, stream>>>(W1, W1_t, 1024, 4096);
  k_transpose_bf16<<<dim3(32, 128), blk, 0, stream>>>(W2, W2_t, 4096, 1024);
  k_f2bf4<<<dim3(4096), blk, 0, stream>>>((const float4*)src, (ushort4*)Xbf, 4096 * 1024 / 4);
  k_rope_table<<<dim3(256), blk, 0, stream>>>(cosT, sinT);
  k_cat3<<<dim3(12), blk, 0, stream>>>(bq, bk, bv, bqkv);
  k_mask_flags<<<dim3(32, 32), blk, 0, stream>>>(mask, mflags);
  // fused QKV projection (M=4096, N=3072, K=1024) -> bf16
  k_gemm256<EPI_BF16><<<dim3(12, 16, 1), blk5, 0, stream>>>(Xbf, Wq_t, bqkv, nullptr, QKVb, 4096, 3072, 1024, 3072, 1024);
  k_rope_heads<<<dim3(MROWS * 512 / 256), blk, 0, stream>>>(QKVb, cosT, sinT, Qh, Kh, Vt);
  // attention: 512 blocks x 8 waves (2 blocks/CU -> 4 waves/SIMD)
  k_attn<<<dim3(16, 32), blk5, 0, stream>>>(Qh, Kh, Vt, mask, mflags, attn_out);
  // O-projection: split-K=4, bf16 partials -> LN1
  k_gemm256<EPI_PARTB><<<dim3(4, 16, 4), blk5, 0, stream>>>(attn_out, Wo_t, nullptr, nullptr, woPb, 4096, 1024, 1024, 1024, 256);
  k_lnp<1><<<dim3(4096), blk, 0, stream>>>(woPb, src, bo, g1, be1, src2f, src2b);
  // FF1 with ReLU
  k_gemm256<EPI_RELU_BF16><<<dim3(16, 16, 1), blk5, 0, stream>>>(src2b, W1_t, b1, nullptr, ff1, 4096, 4096, 1024, 4096, 1024);
  // FF2: split-K=4, bf16 partials -> LN2
  k_gemm256<EPI_PARTB><<<dim3(4, 16, 4), blk5, 0, stream>>>(ff1, W2_t, nullptr, nullptr, ffPb, 4096, 1024, 4096, 1024, 1024);
  k_lnp<0><<<dim3(4096), blk, 0, stream>>>(ffPb, src2f, b2, g2, be2, out, nullptr);
}

// Round 10
// 278.072 us; speedup vs baseline: 1.2449x; 1.1846x over previous
//
#include <hip/hip_runtime.h>
#include <math.h>

#define S_LEN 2048
#define DM 1024
#define NH 16
#define HD 64
#define DFF 4096
#define MROWS 4096  // S_LEN * 2 batch

typedef unsigned short u16;
typedef __attribute__((ext_vector_type(8))) __bf16 bf16x8;
typedef __attribute__((ext_vector_type(4))) float f32x4;
typedef __attribute__((ext_vector_type(16))) float f32x16;
typedef __attribute__((ext_vector_type(4))) int int32x4;

__device__ __forceinline__ u16 f2bf(float f) {
  unsigned u = __float_as_uint(f);
  unsigned r = (u + 0x7fffu + ((u >> 16) & 1u)) >> 16;  // RNE
  return (u16)r;
}

__device__ __forceinline__ float bf2f(u16 u) {
  return __uint_as_float((unsigned)u << 16);
}

__device__ __forceinline__ unsigned cvtpk_bf16(float lo, float hi) {
  unsigned r;
  asm("v_cvt_pk_bf16_f32 %0, %1, %2" : "=v"(r) : "v"(lo), "v"(hi));
  return r;
}

__device__ __forceinline__ void gload_lds16(const void* g, void* l) {
  __builtin_amdgcn_global_load_lds((__attribute__((address_space(1))) void*)g,
                                   (__attribute__((address_space(3))) void*)l, 16, 0, 0);
}

// ---------- fused preprocessing: 6 weight transposes (fp32->bf16) + src f2bf ----------
// flat block ranges: [0,1024)x4 = Wq/Wk/Wv/Wo (1024x1024), [4096,8192) = W1 (1024x4096),
// [8192,12288) = W2 (4096x1024), [12288,16384) = src f2bf.
__global__ __launch_bounds__(256) void k_prep(const float* __restrict__ Wq, const float* __restrict__ Wk,
                                              const float* __restrict__ Wv, const float* __restrict__ Wo,
                                              const float* __restrict__ W1, const float* __restrict__ W2,
                                              u16* __restrict__ Wq_t, u16* __restrict__ Wk_t,
                                              u16* __restrict__ Wv_t, u16* __restrict__ Wo_t,
                                              u16* __restrict__ W1_t, u16* __restrict__ W2_t,
                                              const float4* __restrict__ src4, ushort4* __restrict__ Xbf4) {
  int flat = blockIdx.x;
  if (flat >= 12288) {  // f2bf: 4096 blocks x 256 threads x 4 floats
    int i = (flat - 12288) * 256 + threadIdx.x;
    float4 v = src4[i];
    ushort4 o;
    o.x = f2bf(v.x); o.y = f2bf(v.y); o.z = f2bf(v.z); o.w = f2bf(v.w);
    Xbf4[i] = o;
    return;
  }
  __shared__ float tile[32][33];
  const float* W;
  u16* Wt;
  int local, nx, K, N;
  if (flat < 4096) {
    int z = flat >> 10;
    W = z == 0 ? Wq : z == 1 ? Wk : z == 2 ? Wv : Wo;
    Wt = z == 0 ? Wq_t : z == 1 ? Wk_t : z == 2 ? Wv_t : Wo_t;
    local = flat & 1023; nx = 32; K = 1024; N = 1024;
  } else if (flat < 8192) {
    W = W1; Wt = W1_t; local = flat - 4096; nx = 128; K = 1024; N = 4096;
  } else {
    W = W2; Wt = W2_t; local = flat - 8192; nx = 32; K = 4096; N = 1024;
  }
  int n0 = (local % nx) * 32, k0 = (local / nx) * 32;
  int tx = threadIdx.x & 31, ty = threadIdx.x >> 5;
  #pragma unroll
  for (int r = ty; r < 32; r += 8) tile[r][tx] = W[(size_t)(k0 + r) * N + n0 + tx];
  __syncthreads();
  #pragma unroll
  for (int r = ty; r < 32; r += 8) Wt[(size_t)(n0 + r) * K + k0 + tx] = f2bf(tile[tx][r]);
}

// ---------- fused misc: rope cos/sin table + bias concat + mask tile flags ----------
// flat: [0,256) rope_table; [256,268) cat3; [268,1292) mask_flags (kt = l&31, qt = l>>5)
__global__ __launch_bounds__(256) void k_misc(float* __restrict__ cosT, float* __restrict__ sinT,
                                              const float* __restrict__ bq, const float* __restrict__ bk,
                                              const float* __restrict__ bv, float* __restrict__ bqkv,
                                              const float* __restrict__ mask,
                                              unsigned char* __restrict__ flags) {
  int flat = blockIdx.x;
  if (flat < 256) {
    int idx = flat * 256 + threadIdx.x;
    int s = idx >> 5, i = idx & 31;
    float inv = powf(10000.f, -(float)(2 * i) / 64.f);
    float ang = (float)s * inv;
    cosT[idx] = cosf(ang);
    sinT[idx] = sinf(ang);
    return;
  }
  if (flat < 268) {
    int i = (flat - 256) * 256 + threadIdx.x;
    if (i < 3072) bqkv[i] = i < 1024 ? bq[i] : (i < 2048 ? bk[i - 1024] : bv[i - 2048]);
    return;
  }
  int local = flat - 268;
  int kt = local & 31, qt = local >> 5;
  const float* mp = mask + (size_t)(qt * 64) * S_LEN + kt * 64;
  int tr = threadIdx.x >> 2;
  int tc = (threadIdx.x & 3) * 16;
  int ok = 1;
  #pragma unroll
  for (int c = 0; c < 16; c += 4) {
    float4 v = *(const float4*)(mp + (size_t)tr * S_LEN + tc + c);
    ok &= (v.x >= 0.1f) & (v.y >= 0.1f) & (v.z >= 0.1f) & (v.w >= 0.1f);
  }
  ok = __all(ok) ? 1 : 0;
  __shared__ int sh[4];
  if ((threadIdx.x & 63) == 0) sh[threadIdx.x >> 6] = ok;
  __syncthreads();
  if (threadIdx.x == 0) flags[qt * 32 + kt] = (sh[0] & sh[1] & sh[2] & sh[3]) ? 0 : 1;
}

// ---------- 256x256-tile pipelined bf16 GEMM ----------
enum { EPI_F32 = 0, EPI_RELU_BF16 = 2, EPI_PARTB = 4, EPI_BF16 = 5 };

template <int EPI>
__global__ __launch_bounds__(512, 2) void k_gemm256(const u16* __restrict__ A,
                                                    const u16* __restrict__ Bt,
                                                    const float* __restrict__ bias,
                                                    float* __restrict__ Cf, u16* __restrict__ Cb,
                                                    int M, int N, int K, int ldc, int Kc) {
  __shared__ __attribute__((aligned(16))) u16 As[4][256 * 32];
  __shared__ __attribute__((aligned(16))) u16 Bs[4][256 * 32];

  int nx = gridDim.x;
  int nwg = nx * gridDim.y;
  int flat = blockIdx.y * nx + blockIdx.x;
  int id = (flat & 7) * (nwg >> 3) + (flat >> 3);
  int n0 = (id % nx) * 256;
  int m0 = (id / nx) * 256;
  int kz = blockIdx.z * Kc;

  int tid = threadIdx.x;
  int lane = tid & 63, w = tid >> 6;
  int wm = (w >> 2) * 128, wn = (w & 3) * 64;
  int l15 = lane & 15, l4 = lane >> 4;
  int NT = Kc >> 5;

  const u16* aS[2];
  const u16* bS[2];
  int dslot[2];
  #pragma unroll
  for (int j = 0; j < 2; ++j) {
    int P = j * 512 + tid;
    int r = P >> 2;
    int sl = (P & 3) ^ (r & 3);
    aS[j] = A + (size_t)(m0 + r) * K + kz + sl * 8;
    bS[j] = Bt + (size_t)(n0 + r) * K + kz + sl * 8;
    dslot[j] = j * 512 + w * 64;
  }

  f32x4 acc[8][4] = {};

  #pragma unroll
  for (int t = 0; t < 3; ++t) {
    #pragma unroll
    for (int j = 0; j < 2; ++j) {
      gload_lds16(aS[j] + t * 32, &As[t][dslot[j] * 8]);
      gload_lds16(bS[j] + t * 32, &Bs[t][dslot[j] * 8]);
    }
  }

  for (int t = 0; t < NT; ++t) {
    int buf = t & 3;
    if (t < NT - 2) asm volatile("s_waitcnt vmcnt(8)" ::: "memory");
    else if (t == NT - 2) asm volatile("s_waitcnt vmcnt(4)" ::: "memory");
    else asm volatile("s_waitcnt vmcnt(0)" ::: "memory");
    __builtin_amdgcn_s_barrier();

    if (t + 3 < NT) {
      int tn = t + 3;
      int bn = tn & 3;
      #pragma unroll
      for (int j = 0; j < 2; ++j) {
        gload_lds16(aS[j] + tn * 32, &As[bn][dslot[j] * 8]);
        gload_lds16(bS[j] + tn * 32, &Bs[bn][dslot[j] * 8]);
      }
    }

    bf16x8 af[8], bq[4];
    #pragma unroll
    for (int m = 0; m < 8; ++m) {
      int r = wm + m * 16 + l15;
      af[m] = *(const bf16x8*)&As[buf][r * 32 + (l4 ^ (r & 3)) * 8];
    }
    #pragma unroll
    for (int n = 0; n < 4; ++n) {
      int r = wn + n * 16 + l15;
      bq[n] = *(const bf16x8*)&Bs[buf][r * 32 + (l4 ^ (r & 3)) * 8];
    }
    __builtin_amdgcn_s_setprio(1);
    #pragma unroll
    for (int m = 0; m < 8; ++m)
      #pragma unroll
      for (int n = 0; n < 4; ++n)
        acc[m][n] = __builtin_amdgcn_mfma_f32_16x16x32_bf16(af[m], bq[n], acc[m][n], 0, 0, 0);
    __builtin_amdgcn_s_setprio(0);
  }

  size_t zoff = (size_t)blockIdx.z * M * ldc;
  #pragma unroll
  for (int m = 0; m < 8; ++m) {
    #pragma unroll
    for (int n = 0; n < 4; ++n) {
      int col = n0 + wn + n * 16 + l15;
      float bv = (EPI == EPI_PARTB) ? 0.f : bias[col];
      #pragma unroll
      for (int r = 0; r < 4; ++r) {
        int row = m0 + wm + m * 16 + l4 * 4 + r;
        float v = acc[m][n][r] + bv;
        size_t o = (size_t)row * ldc + col;
        if (EPI == EPI_F32) Cf[o] = v;
        else if (EPI == EPI_RELU_BF16) Cb[o] = f2bf(fmaxf(v, 0.f));
        else if (EPI == EPI_BF16) Cb[o] = f2bf(v);
        else Cb[zoff + o] = f2bf(v);
      }
    }
  }
}

// ---------- RoPE + head-split, vectorized; V transposed through LDS ----------
// Block = (bh, 64 s-rows). Q pre-scaled by log2(e)/sqrt(HD) (exp2 domain).
#define QSCALE 0.180336881f
__global__ __launch_bounds__(256) void k_rope_heads(const u16* __restrict__ QKVb,
                                                    const float* __restrict__ cosT,
                                                    const float* __restrict__ sinT,
                                                    u16* __restrict__ Qh, u16* __restrict__ Kh,
                                                    u16* __restrict__ Vt) {
  __shared__ u16 Vlds[64 * 80];  // [d][s], stride 80 u16 (160 B)
  int bh = blockIdx.y;
  int s0 = blockIdx.x * 64;
  int b = bh >> 4, h = bh & 15;
  int tid = threadIdx.x;
  int sr = tid >> 2, dg = (tid & 3) * 16;
  int s = s0 + sr;
  size_t rowbase = (size_t)(s * 2 + b) * 3072 + h * 64 + dg;

  float4 c0 = *(const float4*)&cosT[s * 32 + (dg >> 1)];
  float4 c1 = *(const float4*)&cosT[s * 32 + (dg >> 1) + 4];
  float4 sn0 = *(const float4*)&sinT[s * 32 + (dg >> 1)];
  float4 sn1 = *(const float4*)&sinT[s * 32 + (dg >> 1) + 4];
  float cs[8] = {c0.x, c0.y, c0.z, c0.w, c1.x, c1.y, c1.z, c1.w};
  float sn[8] = {sn0.x, sn0.y, sn0.z, sn0.w, sn1.x, sn1.y, sn1.z, sn1.w};

  // Q (rope + scale)
  {
    uint4 a = *(const uint4*)&QKVb[rowbase];
    uint4 bbu = *(const uint4*)&QKVb[rowbase + 8];
    unsigned ws[8] = {a.x, a.y, a.z, a.w, bbu.x, bbu.y, bbu.z, bbu.w};
    unsigned o[8];
    #pragma unroll
    for (int j = 0; j < 8; ++j) {
      float lo = bf2f((u16)(ws[j] & 0xffff)), hi = bf2f((u16)(ws[j] >> 16));
      o[j] = cvtpk_bf16((lo * cs[j] - hi * sn[j]) * QSCALE, (hi * cs[j] + lo * sn[j]) * QSCALE);
    }
    u16* qp = &Qh[((size_t)bh * S_LEN + s) * 64 + dg];
    *(uint4*)qp = (uint4){o[0], o[1], o[2], o[3]};
    *(uint4*)(qp + 8) = (uint4){o[4], o[5], o[6], o[7]};
  }
  // K (rope)
  {
    uint4 a = *(const uint4*)&QKVb[rowbase + 1024];
    uint4 bbu = *(const uint4*)&QKVb[rowbase + 1032];
    unsigned ws[8] = {a.x, a.y, a.z, a.w, bbu.x, bbu.y, bbu.z, bbu.w};
    unsigned o[8];
    #pragma unroll
    for (int j = 0; j < 8; ++j) {
      float lo = bf2f((u16)(ws[j] & 0xffff)), hi = bf2f((u16)(ws[j] >> 16));
      o[j] = cvtpk_bf16(lo * cs[j] - hi * sn[j], hi * cs[j] + lo * sn[j]);
    }
    u16* kp = &Kh[((size_t)bh * S_LEN + s) * 64 + dg];
    *(uint4*)kp = (uint4){o[0], o[1], o[2], o[3]};
    *(uint4*)(kp + 8) = (uint4){o[4], o[5], o[6], o[7]};
  }
  // V: copy to LDS transposed, then coalesced rows to Vt
  {
    uint4 a = *(const uint4*)&QKVb[rowbase + 2048];
    uint4 bbu = *(const uint4*)&QKVb[rowbase + 2056];
    unsigned ws[8] = {a.x, a.y, a.z, a.w, bbu.x, bbu.y, bbu.z, bbu.w};
    #pragma unroll
    for (int j = 0; j < 8; ++j) {
      Vlds[(dg + 2 * j) * 80 + sr] = (u16)(ws[j] & 0xffff);
      Vlds[(dg + 2 * j + 1) * 80 + sr] = (u16)(ws[j] >> 16);
    }
  }
  __syncthreads();
  {
    int d = tid >> 2, sg = (tid & 3) * 16;
    uint4 v0 = *(const uint4*)&Vlds[d * 80 + sg];
    uint4 v1 = *(const uint4*)&Vlds[d * 80 + sg + 8];
    u16* vp = &Vt[((size_t)bh * 64 + d) * S_LEN + s0 + sg];
    *(uint4*)vp = v0;
    *(uint4*)(vp + 8) = v1;
  }
}

// ---------- flash attention (R7 structure): swapped-QK^T 32x32x16, in-register softmax,
//            double-buffered 128-key tiles, XCD-grouped heads, + s_setprio on MFMA ----------
__global__ __launch_bounds__(256) void k_attn(const u16* __restrict__ Qh, const u16* __restrict__ Kh,
                                              const u16* __restrict__ Vt,
                                              const float* __restrict__ mask,
                                              const unsigned char* __restrict__ flags,
                                              u16* __restrict__ Out) {
  __shared__ __attribute__((aligned(16))) u16 Ks[2][128 * 64];
  __shared__ __attribute__((aligned(16))) u16 Vs[2][64 * 128];
  int f = blockIdx.y * gridDim.x + blockIdx.x;  // grid (16, 32)
  int xcd = f & 7, ii = f >> 3;
  int bh = xcd * 4 + (ii >> 4);
  int q0 = (ii & 15) * 128;
  int b = bh >> 4, h = bh & 15;
  int tid = threadIdx.x, lane = tid & 63, w = tid >> 6;
  int l31 = lane & 31, l5 = lane >> 5;

  int qrow = q0 + w * 32 + l31;
  int qt = qrow >> 6;  // wave-uniform

  bf16x8 qf[4];
  {
    const u16* qp = Qh + ((size_t)bh * S_LEN + qrow) * 64 + l5 * 8;
    #pragma unroll
    for (int dc = 0; dc < 4; ++dc) qf[dc] = *(const bf16x8*)(qp + dc * 16);
  }

  const u16* Kbase = Kh + (size_t)bh * S_LEN * 64;
  const u16* Vbase = Vt + (size_t)bh * 64 * S_LEN;

  int ksid[4], vsid[4];
  const u16* kg[4];
  const u16* vg[4];
  #pragma unroll
  for (int i = 0; i < 4; ++i) {
    int sid = i * 256 + tid;
    ksid[i] = sid;
    int kr = sid >> 3, kslot = sid & 7;
    kg[i] = Kbase + (size_t)kr * 64 + (kslot ^ (kr & 7)) * 8;
    vsid[i] = sid;
    int vr = sid >> 4, vslot = sid & 15;
    vg[i] = Vbase + (size_t)vr * S_LEN + ((vslot ^ (vr & 15))) * 8;
  }

  float m_run = -1e30f, l_run = 0.f;
  f32x16 oA = {}, oB = {};

  const int NTILE = S_LEN / 128;
  #pragma unroll
  for (int i = 0; i < 4; ++i) {
    gload_lds16(kg[i], &Ks[0][ksid[i] * 8]);
    gload_lds16(vg[i], &Vs[0][vsid[i] * 8]);
  }

  for (int t = 0; t < NTILE; ++t) {
    int cur = t & 1;
    int kv0 = t * 128;
    asm volatile("s_waitcnt vmcnt(0)" ::: "memory");
    __builtin_amdgcn_s_barrier();
    if (t + 1 < NTILE) {
      int kvn = (t + 1) * 128;
      #pragma unroll
      for (int i = 0; i < 4; ++i) {
        gload_lds16(kg[i] + (size_t)kvn * 64, &Ks[cur ^ 1][ksid[i] * 8]);
        gload_lds16(vg[i] + kvn, &Vs[cur ^ 1][vsid[i] * 8]);
      }
    }

    #pragma unroll
    for (int ksub = 0; ksub < 2; ++ksub) {
      int koff = ksub * 64;
      f32x16 sA = {}, sB = {};
      __builtin_amdgcn_s_setprio(1);
      #pragma unroll
      for (int dc = 0; dc < 4; ++dc) {
        int r0 = koff + l31;
        int r1 = koff + 32 + l31;
        int slot = (dc * 2 + l5) ^ (l31 & 7);
        bf16x8 ka0 = *(const bf16x8*)&Ks[cur][r0 * 64 + slot * 8];
        bf16x8 ka1 = *(const bf16x8*)&Ks[cur][r1 * 64 + slot * 8];
        sA = __builtin_amdgcn_mfma_f32_32x32x16_bf16(ka0, qf[dc], sA, 0, 0, 0);
        sB = __builtin_amdgcn_mfma_f32_32x32x16_bf16(ka1, qf[dc], sB, 0, 0, 0);
      }
      __builtin_amdgcn_s_setprio(0);

      int fl = flags[qt * 32 + ((kv0 + koff) >> 6)];
      if (fl) {
        const float* mrow = mask + (size_t)qrow * S_LEN + kv0 + koff;
        #pragma unroll
        for (int r = 0; r < 16; ++r) {
          int key = (r & 3) + 8 * (r >> 2) + 4 * l5;
          if (mrow[key] < 0.1f) sA[r] = -1e30f;
          if (mrow[key + 32] < 0.1f) sB[r] = -1e30f;
        }
      }

      float pm = m_run;
      #pragma unroll
      for (int r = 0; r < 16; ++r) pm = fmaxf(pm, fmaxf(sA[r], sB[r]));
      pm = fmaxf(pm, __shfl_xor(pm, 32, 64));
      if (!__all(pm <= m_run + 8.f)) {  // defer-max (log2 units)
        float corr = __builtin_amdgcn_exp2f(m_run - pm);
        m_run = pm;
        l_run *= corr;
        #pragma unroll
        for (int r = 0; r < 16; ++r) { oA[r] *= corr; oB[r] *= corr; }
      }
      float ps = 0.f;
      #pragma unroll
      for (int r = 0; r < 16; ++r) {
        sA[r] = __builtin_amdgcn_exp2f(sA[r] - m_run);
        sB[r] = __builtin_amdgcn_exp2f(sB[r] - m_run);
        ps += sA[r] + sB[r];
      }
      l_run += ps;

      __builtin_amdgcn_s_setprio(1);
      #pragma unroll
      for (int kh = 0; kh < 2; ++kh) {
        f32x16 s = kh ? sB : sA;
        #pragma unroll
        for (int c = 0; c < 2; ++c) {
          int base = c * 8;
          unsigned u0 = cvtpk_bf16(s[base + 0], s[base + 1]);
          unsigned u1 = cvtpk_bf16(s[base + 2], s[base + 3]);
          unsigned u2 = cvtpk_bf16(s[base + 4], s[base + 5]);
          unsigned u3 = cvtpk_bf16(s[base + 6], s[base + 7]);
          asm volatile("v_permlane32_swap_b32 %0, %1" : "+v"(u0), "+v"(u2));
          asm volatile("v_permlane32_swap_b32 %0, %1" : "+v"(u1), "+v"(u3));
          int32x4 wds = {(int)u0, (int)u1, (int)u2, (int)u3};
          bf16x8 pb = *(bf16x8*)&wds;
          int kslot = ksub * 8 + (kh * 2 + c) * 2 + l5;
          int vr0 = l31, vr1 = 32 + l31;
          bf16x8 va0 = *(const bf16x8*)&Vs[cur][vr0 * 128 + (kslot ^ (vr0 & 15)) * 8];
          bf16x8 va1 = *(const bf16x8*)&Vs[cur][vr1 * 128 + (kslot ^ (vr1 & 15)) * 8];
          oA = __builtin_amdgcn_mfma_f32_32x32x16_bf16(va0, pb, oA, 0, 0, 0);
          oB = __builtin_amdgcn_mfma_f32_32x32x16_bf16(va1, pb, oB, 0, 0, 0);
        }
      }
      __builtin_amdgcn_s_setprio(0);
    }
  }

  float l_tot = l_run + __shfl_xor(l_run, 32, 64);
  float inv = 1.f / l_tot;
  int mrow = qrow * 2 + b;
  u16* op = Out + (size_t)mrow * DM + h * 64;
  #pragma unroll
  for (int db = 0; db < 2; ++db) {
    f32x16 o = db ? oB : oA;
    #pragma unroll
    for (int g = 0; g < 4; ++g) {
      int d0 = db * 32 + 8 * g + 4 * l5;
      ushort4 st;
      st.x = f2bf(o[4 * g + 0] * inv);
      st.y = f2bf(o[4 * g + 1] * inv);
      st.z = f2bf(o[4 * g + 2] * inv);
      st.w = f2bf(o[4 * g + 3] * inv);
      *(ushort4*)(op + d0) = st;
    }
  }
}

// ---------- fused LayerNorm: x = addf + bvec + sum of 4 bf16 partials; LN -> Yf (+Yb) ----------
__device__ __forceinline__ float wave_sum(float v) {
  #pragma unroll
  for (int off = 32; off >= 1; off >>= 1) v += __shfl_xor(v, off, 64);
  return v;
}

template <int WB>
__global__ __launch_bounds__(256) void k_lnp(const u16* __restrict__ pb, const float* __restrict__ addf,
                                             const float* __restrict__ bvec,
                                             const float* __restrict__ gw, const float* __restrict__ bw,
                                             float* __restrict__ Yf, u16* __restrict__ Yb) {
  int m = blockIdx.x;
  int tid = threadIdx.x, lane = tid & 63, w = tid >> 6;
  __shared__ float part[4];
  __shared__ float shv[2];
  float4 sc = ((const float4*)(addf + (size_t)m * DM))[tid];
  float4 bv = ((const float4*)bvec)[tid];
  float vx = sc.x + bv.x, vy = sc.y + bv.y, vz = sc.z + bv.z, vw = sc.w + bv.w;
  #pragma unroll
  for (int z = 0; z < 4; ++z) {
    ushort4 qv = ((const ushort4*)(pb + (size_t)z * MROWS * DM + (size_t)m * DM))[tid];
    vx += bf2f(qv.x); vy += bf2f(qv.y); vz += bf2f(qv.z); vw += bf2f(qv.w);
  }
  float s = wave_sum(vx + vy + vz + vw);
  if (lane == 0) part[w] = s;
  __syncthreads();
  if (tid == 0) shv[0] = (part[0] + part[1] + part[2] + part[3]) * (1.f / DM);
  __syncthreads();
  float mu = shv[0];
  float d0 = vx - mu, d1 = vy - mu, d2 = vz - mu, d3 = vw - mu;
  float q = wave_sum(d0 * d0 + d1 * d1 + d2 * d2 + d3 * d3);
  if (lane == 0) part[w] = q;
  __syncthreads();
  if (tid == 0) shv[1] = rsqrtf((part[0] + part[1] + part[2] + part[3]) * (1.f / DM) + 1e-5f);
  __syncthreads();
  float rstd = shv[1];
  float4 g4 = ((const float4*)gw)[tid];
  float4 b4 = ((const float4*)bw)[tid];
  float y0 = d0 * rstd * g4.x + b4.x;
  float y1 = d1 * rstd * g4.y + b4.y;
  float y2 = d2 * rstd * g4.z + b4.z;
  float y3 = d3 * rstd * g4.w + b4.w;
  ((float4*)(Yf + (size_t)m * DM))[tid] = make_float4(y0, y1, y2, y3);
  if (WB) {
    ushort4 o;
    o.x = f2bf(y0); o.y = f2bf(y1); o.z = f2bf(y2); o.w = f2bf(y3);
    ((ushort4*)(Yb + (size_t)m * DM))[tid] = o;
  }
}

extern "C" void kernel_launch(void* const* d_in, const int* in_sizes, int n_in,
                              void* d_out, int out_size, void* d_ws, size_t ws_size,
                              hipStream_t stream) {
  (void)in_sizes; (void)n_in; (void)out_size; (void)ws_size;
  const float* src  = (const float*)d_in[0];
  const float* mask = (const float*)d_in[1];
  const float* Wq = (const float*)d_in[2];  const float* bq  = (const float*)d_in[3];
  const float* Wk = (const float*)d_in[4];  const float* bk  = (const float*)d_in[5];
  const float* Wv = (const float*)d_in[6];  const float* bv  = (const float*)d_in[7];
  const float* Wo = (const float*)d_in[8];  const float* bo  = (const float*)d_in[9];
  const float* W1 = (const float*)d_in[10]; const float* b1  = (const float*)d_in[11];
  const float* W2 = (const float*)d_in[12]; const float* b2  = (const float*)d_in[13];
  const float* g1 = (const float*)d_in[14]; const float* be1 = (const float*)d_in[15];
  const float* g2 = (const float*)d_in[16]; const float* be2 = (const float*)d_in[17];
  float* out = (float*)d_out;

  char* base = (char*)d_ws;
  size_t off = 0;
  auto carve = [&](size_t bytes) -> void* {
    void* r = base + off;
    off += (bytes + 255) & ~(size_t)255;
    return r;
  };
  u16* Wq_t = (u16*)carve(2ull * 1024 * 1024);  // Wq_t/Wk_t/Wv_t contiguous -> fused N=3072 GEMM
  u16* Wk_t = (u16*)carve(2ull * 1024 * 1024);
  u16* Wv_t = (u16*)carve(2ull * 1024 * 1024);
  u16* Wo_t = (u16*)carve(2ull * 1024 * 1024);
  u16* W1_t = (u16*)carve(2ull * 4096 * 1024);
  u16* W2_t = (u16*)carve(2ull * 1024 * 4096);
  u16* Xbf  = (u16*)carve(2ull * 4096 * 1024);
  float* cosT = (float*)carve(4ull * 2048 * 32);
  float* sinT = (float*)carve(4ull * 2048 * 32);
  float* bqkv = (float*)carve(4ull * 3072);
  unsigned char* mflags = (unsigned char*)carve(1024);
  u16* attn_out = (u16*)carve(2ull * 4096 * 1024);
  float* src2f = (float*)carve(4ull * 4096 * 1024);     // dedicated: live LN1 -> LN2
  float* QKV = (float*)carve(4ull * 4096 * 3072);       // 48MB region, multiply reused
  u16* Qh = (u16*)carve(2ull * 32 * 2048 * 64);         // 8MB
  u16* Kh = (u16*)carve(2ull * 32 * 2048 * 64);         // 8MB
  u16* Vt = (u16*)carve(2ull * 32 * 2048 * 64);         // 8MB
  // Aliases (lifetimes):
  //   QKVb = QKV region as bf16 (24MB): dead after rope_heads.
  //   woPb = QKV+0 (4 x 8MB bf16): Wo split-K=4 partials, consumed by LN1.
  //   ff1  = QKV+0 (32MB bf16): written by FF1 after LN1 (woPb dead).
  //   ffPb = QKV+32MB..+64MB (4 x 8MB bf16): FF2 partials; spans QKV tail + Qh + Kh
  //          (Qh/Kh dead after attn). Consumed by LN2.
  //   src2b = Vt (8MB bf16): Vt dead after attn; consumed by FF1.
  u16* QKVb = (u16*)QKV;
  u16* woPb = (u16*)QKV;
  u16* ff1 = (u16*)QKV;
  u16* ffPb = (u16*)((char*)QKV + 32ull * 1024 * 1024);
  u16* src2b = (u16*)Vt;

  dim3 blk(256);
  dim3 blk5(512);
  // fused preprocessing: 6 transposes + src f2bf in one dispatch
  k_prep<<<dim3(16384), blk, 0, stream>>>(Wq, Wk, Wv, Wo, W1, W2, Wq_t, Wk_t, Wv_t, Wo_t,
                                          W1_t, W2_t, (const float4*)src, (ushort4*)Xbf);
  // fused misc: rope table + bias concat + mask flags
  k_misc<<<dim3(1292), blk, 0, stream>>>(cosT, sinT, bq, bk, bv, bqkv, mask, mflags);
  // fused QKV projection (M=4096, N=3072, K=1024) -> bf16
  k_gemm256<EPI_BF16><<<dim3(12, 16, 1), blk5, 0, stream>>>(Xbf, Wq_t, bqkv, nullptr, QKVb, 4096, 3072, 1024, 3072, 1024);
  k_rope_heads<<<dim3(32, 32), blk, 0, stream>>>(QKVb, cosT, sinT, Qh, Kh, Vt);
  // attention: 512 blocks x 4 waves (2 blocks/CU), R7 structure + setprio
  k_attn<<<dim3(16, 32), blk, 0, stream>>>(Qh, Kh, Vt, mask, mflags, attn_out);
  // O-projection: split-K=4, bf16 partials -> LN1
  k_gemm256<EPI_PARTB><<<dim3(4, 16, 4), blk5, 0, stream>>>(attn_out, Wo_t, nullptr, nullptr, woPb, 4096, 1024, 1024, 1024, 256);
  k_lnp<1><<<dim3(4096), blk, 0, stream>>>(woPb, src, bo, g1, be1, src2f, src2b);
  // FF1 with ReLU
  k_gemm256<EPI_RELU_BF16><<<dim3(16, 16, 1), blk5, 0, stream>>>(src2b, W1_t, b1, nullptr, ff1, 4096, 4096, 1024, 4096, 1024);
  // FF2: split-K=4, bf16 partials -> LN2
  k_gemm256<EPI_PARTB><<<dim3(4, 16, 4), blk5, 0, stream>>>(ff1, W2_t, nullptr, nullptr, ffPb, 4096, 1024, 4096, 1024, 1024);
  k_lnp<0><<<dim3(4096), blk, 0, stream>>>(ffPb, src2f, b2, g2, be2, out, nullptr);
}